// Round 4
// baseline (274.457 us; speedup 1.0000x reference)
//
#include <hip/hip_runtime.h>
#include <hip/hip_bf16.h>
#include <hip/hip_fp16.h>

#define H 128           // H_IN == H_OUT == 128
#define BW 128          // nodes per coarse bucket
#define BSH 7           // log2(BW)
#define NB 256          // partition blocks for counting sort

typedef __attribute__((ext_vector_type(8))) short short8;
typedef __attribute__((ext_vector_type(4))) float f32x4;

__device__ inline unsigned short f2bf(float f) {
    union { float f; unsigned int u; } v; v.f = f;
    unsigned int r = (v.u + 0x7fffu + ((v.u >> 16) & 1u)) >> 16;
    return (unsigned short)r;
}
__device__ inline float bf2f(unsigned short h) {
    union { unsigned int u; float f; } v; v.u = ((unsigned int)h) << 16;
    return v.f;
}

// ---------------------------------------------------------------------------
// Fused: per-row u8 quantization (blocks 0..qb-1), W-pack (blocks 0..7),
// and the p1 edge histogram (blocks qb..qb+NB-1).
__global__ __launch_bounds__(256) void quant_hist_kernel(const float* __restrict__ x,
                                                         const float* __restrict__ Wc,
                                                         const float* __restrict__ Ws,
                                                         const int* __restrict__ ei,
                                                         uint* __restrict__ xq,
                                                         float* __restrict__ invs,
                                                         short8* __restrict__ wp,
                                                         int* __restrict__ counts,
                                                         int N, int E, int nbu,
                                                         int chunk, int qb) {
    __shared__ int h[1024];
    if (blockIdx.x >= qb) {
        // ---- p1 histogram role ----
        const int b = blockIdx.x - qb;
        for (int i = threadIdx.x; i < nbu; i += 256) h[i] = 0;
        __syncthreads();
        const int lo = b * chunk;
        const int hi = min(E, lo + chunk);
        for (int e = lo + threadIdx.x; e < hi; e += 256)
            atomicAdd(&h[ei[E + e] >> BSH], 1);
        __syncthreads();
        for (int i = threadIdx.x; i < nbu; i += 256) counts[b * nbu + i] = h[i];
        return;
    }
    // ---- quant role ----
    int node = blockIdx.x * 8 + (threadIdx.x >> 5);
    if (node < N) {
        int l32 = threadIdx.x & 31;
        float4 v = ((const float4*)x)[node * 32 + l32];
        float m = fmaxf(fmaxf(fabsf(v.x), fabsf(v.y)), fmaxf(fabsf(v.z), fabsf(v.w)));
        #pragma unroll
        for (int mk = 1; mk < 32; mk <<= 1) m = fmaxf(m, __shfl_xor(m, mk));
        m = fmaxf(m, 1e-30f);
        float s = 127.0f / m;
        int q0 = min(255, max(0, (int)rintf(v.x * s) + 128));
        int q1 = min(255, max(0, (int)rintf(v.y * s) + 128));
        int q2 = min(255, max(0, (int)rintf(v.z * s) + 128));
        int q3 = min(255, max(0, (int)rintf(v.w * s) + 128));
        xq[node * 32 + l32] = (uint)q0 | ((uint)q1 << 8) | ((uint)q2 << 16) | ((uint)q3 << 24);
        if (l32 == 0) invs[node] = m / 127.0f;
    }
    if (blockIdx.x < 8) {
        // ---- W-pack role ----
        int t = blockIdx.x * 256 + threadIdx.x;   // 0..2047
        int lane = t & 63;
        int nt = (t >> 6) & 7;
        int ks = t >> 9;
        int kbase = ks * 32 + (lane >> 4) * 8;
        int col = nt * 16 + (lane & 15);
        short8 whc, whs, wls;
        #pragma unroll
        for (int j = 0; j < 8; ++j) {
            float wc = Wc[(kbase + j) * H + col];
            float ws = Ws[(kbase + j) * H + col];
            unsigned short hc = f2bf(wc);
            unsigned short hs = f2bf(ws);
            whc[j] = (short)hc;
            whs[j] = (short)hs;
            wls[j] = (short)f2bf(ws - bf2f(hs));
        }
        int base = (ks * 8 + nt) * 64 + lane;
        wp[base] = whc;
        wp[2048 + base] = whs;
        wp[4096 + base] = wls;
    }
}

// P2: per bucket, exclusive scan of its NB block-counts
__global__ __launch_bounds__(NB) void p2_scan(const int* __restrict__ counts,
                                              int* __restrict__ scanned,
                                              int* __restrict__ btot, int nbu) {
    __shared__ int s[NB];
    const int k = blockIdx.x, t = threadIdx.x;
    int v = counts[t * nbu + k];
    s[t] = v;
    __syncthreads();
    for (int off = 1; off < NB; off <<= 1) {
        int a = (t >= off) ? s[t - off] : 0;
        __syncthreads();
        s[t] += a;
        __syncthreads();
    }
    scanned[t * nbu + k] = s[t] - v;
    if (t == NB - 1) btot[k] = s[t];
}

// P5: scatter packed edges into exact slots (no global atomics).
__global__ __launch_bounds__(256) void p5_scatter(const int* __restrict__ ei,
                                                  const int* __restrict__ btot,
                                                  const int* __restrict__ scanned,
                                                  int* __restrict__ tmp,
                                                  int* __restrict__ cstart,
                                                  int E, int nbu, int chunk) {
    __shared__ int sc[1024];
    __shared__ int part[256];
    __shared__ int lb[1024];
    const int t = threadIdx.x;
    const int b = blockIdx.x;
    const int base = t * 4;
    int v0 = (base + 0 < nbu) ? btot[base + 0] : 0;
    int v1 = (base + 1 < nbu) ? btot[base + 1] : 0;
    int v2 = (base + 2 < nbu) ? btot[base + 2] : 0;
    int v3 = (base + 3 < nbu) ? btot[base + 3] : 0;
    int s1 = v0 + v1, s2 = s1 + v2, s3 = s2 + v3;
    part[t] = s3;
    __syncthreads();
    for (int off = 1; off < 256; off <<= 1) {
        int a = (t >= off) ? part[t - off] : 0;
        __syncthreads();
        part[t] += a;
        __syncthreads();
    }
    int add = (t > 0) ? part[t - 1] : 0;
    sc[base + 0] = add;
    sc[base + 1] = add + v0;
    sc[base + 2] = add + s1;
    sc[base + 3] = add + s2;
    __syncthreads();
    if (b == 0) {
        for (int k = t; k < nbu; k += 256) cstart[k] = sc[k];
        if (t == 0) cstart[nbu] = E;
    }
    for (int k = t; k < nbu; k += 256) lb[k] = sc[k] + scanned[b * nbu + k];
    __syncthreads();
    const int lo = b * chunk;
    const int hi = min(E, lo + chunk);
    for (int e = lo + t; e < hi; e += 256) {
        int s = ei[e], d = ei[E + e];
        int slot = atomicAdd(&lb[d >> BSH], 1);
        tmp[slot] = ((d & (BW - 1)) << 17) | s;
    }
}

// csrA: per bucket, local histogram + parallel scan -> rstart, dinv, ainv, selfw
__global__ __launch_bounds__(256) void csra_kernel(const int* __restrict__ tmp,
                                                   const int* __restrict__ cstart,
                                                   const float* __restrict__ invs,
                                                   int* __restrict__ rstart,
                                                   float* __restrict__ dinv,
                                                   float* __restrict__ ainv,
                                                   float* __restrict__ selfw,
                                                   int N, int E) {
    __shared__ int ldeg[BW];
    __shared__ int lscan[BW];   // inclusive scan
    const int b = blockIdx.x;
    const int nstart = b << BSH;
    const int estart = cstart[b];
    const int eend = cstart[b + 1];
    const int t = threadIdx.x;

    if (t < BW) ldeg[t] = 0;
    __syncthreads();
    for (int i = estart + t; i < eend; i += 256)
        atomicAdd(&ldeg[(tmp[i] >> 17) & (BW - 1)], 1);
    __syncthreads();
    if (t < BW) lscan[t] = ldeg[t];
    __syncthreads();
    #pragma unroll
    for (int off = 1; off < BW; off <<= 1) {
        int a = 0;
        if (t < BW && t >= off) a = lscan[t - off];
        __syncthreads();
        if (t < BW) lscan[t] += a;
        __syncthreads();
    }
    if (t < BW) {
        int excl = lscan[t] - ldeg[t];
        int n = nstart + t;
        if (n < N) {
            float iv = invs[n];
            float dv = rsqrtf((float)ldeg[t] + 2.0f);
            rstart[n] = estart + excl;
            dinv[n] = dv;
            ainv[n] = dv * iv;
            selfw[n] = 2.0f * dv * dv * iv;   // self-loop weight incl dequant scale
        }
    }
    if (b == 0 && t == 0) rstart[N] = E;
}

// csrB: scatter src + precomputed f16 edge weight into final CSR slots.
__global__ __launch_bounds__(256) void csrb_kernel(const int* __restrict__ tmp,
                                                   const int* __restrict__ cstart,
                                                   const int* __restrict__ rstart,
                                                   const float* __restrict__ dinv,
                                                   const float* __restrict__ ainv,
                                                   int* __restrict__ entries,
                                                   unsigned short* __restrict__ wgt,
                                                   int N, int E) {
    __shared__ int lcur[BW];
    __shared__ float ldv[BW];
    const int b = blockIdx.x;
    const int nstart = b << BSH;
    const int t = threadIdx.x;
    if (t < BW) {
        int n = nstart + t;
        lcur[t] = (n < N) ? rstart[n] : 0;
        ldv[t] = (n < N) ? dinv[n] : 0.f;
    }
    __syncthreads();
    const int estart = cstart[b];
    const int eend = cstart[b + 1];
    for (int i = estart + t; i < eend; i += 256) {
        int v = tmp[i];
        int ld = (v >> 17) & (BW - 1);
        int src = v & 0x1FFFF;
        float w = ainv[src] * ldv[ld];
        int slot = atomicAdd(&lcur[ld], 1);
        entries[slot] = src;
        wgt[slot] = __half_as_ushort(__float2half(w));
    }
}

// ---------------------------------------------------------------------------
// Gather aggregation on u8 x. One wave per node; QUARTER-wave (16 lanes x
// uint2 = 8 features each) per edge -> 4 edges per iteration.
// CHANGE vs round-3: each quarter loads its edge's {entries,wgt} DIRECTLY
// (uniform address across the 16 lanes -> one broadcast request, L1-hot
// since a node's edge list is contiguous). This removes the 64-wide strip
// prologue and the two ds_bpermute broadcasts per iteration.
__global__ __launch_bounds__(256) void agg_kernel(const int* __restrict__ entries,
                                                  const unsigned short* __restrict__ wgt,
                                                  const int* __restrict__ rstart,
                                                  const float* __restrict__ selfw,
                                                  const uint* __restrict__ xq,
                                                  unsigned short* __restrict__ z, int N) {
    int node = blockIdx.x * 4 + (threadIdx.x >> 6);
    if (node >= N) return;
    const int lane = threadIdx.x & 63;
    const int l16 = lane & 15;
    const int q4 = lane >> 4;
    const uint2* x2 = (const uint2*)xq;   // 8 features per element, 16 per row

    // independent early loads: overlap with the edge chain
    int start = rstart[node];
    int end = rstart[node + 1];
    float sw = selfw[node];
    uint2 qs = x2[node * 16 + l16];

    float a0 = 0.f, a1 = 0.f, a2 = 0.f, a3 = 0.f;
    float a4 = 0.f, a5 = 0.f, a6 = 0.f, a7 = 0.f;
    float sumw = 0.f;

    const int deg = end - start;
    const int iters = (deg + 3) >> 2;
    #pragma unroll 4
    for (int t = 0; t < iters; ++t) {
        int idx = 4 * t + q4;
        if (idx < deg) {
            int ss = entries[start + idx];
            float wv = __half2float(__ushort_as_half(wgt[start + idx]));
            uint2 q = x2[ss * 16 + l16];
            sumw += wv;
            a0 += wv * (float)(q.x & 0xffu);
            a1 += wv * (float)((q.x >> 8) & 0xffu);
            a2 += wv * (float)((q.x >> 16) & 0xffu);
            a3 += wv * (float)(q.x >> 24);
            a4 += wv * (float)(q.y & 0xffu);
            a5 += wv * (float)((q.y >> 8) & 0xffu);
            a6 += wv * (float)((q.y >> 16) & 0xffu);
            a7 += wv * (float)(q.y >> 24);
        }
    }

    // combine quarters (all lanes end with totals; lanes 0-15 store)
    #define R2(A) A += __shfl_xor(A, 16); A += __shfl_xor(A, 32);
    R2(a0) R2(a1) R2(a2) R2(a3) R2(a4) R2(a5) R2(a6) R2(a7) R2(sumw)
    #undef R2

    if (q4 == 0) {
        // self-loop from own quantized row
        sumw += sw;
        a0 += sw * (float)(qs.x & 0xffu);
        a1 += sw * (float)((qs.x >> 8) & 0xffu);
        a2 += sw * (float)((qs.x >> 16) & 0xffu);
        a3 += sw * (float)(qs.x >> 24);
        a4 += sw * (float)(qs.y & 0xffu);
        a5 += sw * (float)((qs.y >> 8) & 0xffu);
        a6 += sw * (float)((qs.y >> 16) & 0xffu);
        a7 += sw * (float)(qs.y >> 24);
        float off = 128.f * sumw;
        uint4 o;
        o.x = (uint)f2bf(a0 - off) | ((uint)f2bf(a1 - off) << 16);
        o.y = (uint)f2bf(a2 - off) | ((uint)f2bf(a3 - off) << 16);
        o.z = (uint)f2bf(a4 - off) | ((uint)f2bf(a5 - off) << 16);
        o.w = (uint)f2bf(a6 - off) | ((uint)f2bf(a7 - off) << 16);
        ((uint4*)z)[node * 16 + l16] = o;
    }
}

// ---------------------------------------------------------------------------
// MFMA GEMM: out = ELU( z@Wc + x@Ws + bc + bsk ), split-bf16 on the x path.
// CHANGE vs round-3: wp is staged per-ks in LDS (24KB, cooperative load once
// per block) instead of every wave streaming all 96KB from L2 -- cuts wp L2
// traffic 4x (600MB -> 150MB) and converts 72 VMEM instrs/thread to ds_reads.
__global__ __launch_bounds__(256) void gemm_kernel(const unsigned short* __restrict__ zb,
                                                   const float* __restrict__ x,
                                                   const short8* __restrict__ wp,
                                                   const float* __restrict__ bc,
                                                   const float* __restrict__ bsk,
                                                   float* __restrict__ out, int N) {
    __shared__ short8 bsm[1536];   // 3 planes x 8 nt x 64 lanes = 24KB
    const int tid = threadIdx.x;
    const int lane = tid & 63;
    const int wave = tid >> 6;
    const int m = lane & 15;
    const int quad = lane >> 4;
    const int row = blockIdx.x * 64 + wave * 16 + m;
    const bool rowok = row < N;

    f32x4 acc[8];
    #pragma unroll
    for (int i = 0; i < 8; ++i) acc[i] = (f32x4){0.f, 0.f, 0.f, 0.f};

    #pragma unroll
    for (int ks = 0; ks < 4; ++ks) {
        const int k0 = ks * 32 + quad * 8;
        // issue A-side loads first (independent of staging)
        short8 za = {0, 0, 0, 0, 0, 0, 0, 0};
        short8 xa_h = {0, 0, 0, 0, 0, 0, 0, 0};
        short8 xa_l = {0, 0, 0, 0, 0, 0, 0, 0};
        if (rowok) {
            za = ((const short8*)zb)[(row * H + k0) >> 3];
            float4 a = *(const float4*)&x[row * H + k0];
            float4 b = *(const float4*)&x[row * H + k0 + 4];
            float xv[8] = {a.x, a.y, a.z, a.w, b.x, b.y, b.z, b.w};
            #pragma unroll
            for (int j = 0; j < 8; ++j) {
                unsigned short h = f2bf(xv[j]);
                xa_h[j] = (short)h;
                xa_l[j] = (short)f2bf(xv[j] - bf2f(h));
            }
        }
        // stage this ks's 3 B-planes into LDS (barrier protects prev reads)
        __syncthreads();
        #pragma unroll
        for (int p = 0; p < 3; ++p) {
            bsm[p * 512 + tid]       = wp[p * 2048 + ks * 512 + tid];
            bsm[p * 512 + 256 + tid] = wp[p * 2048 + ks * 512 + 256 + tid];
        }
        __syncthreads();
        #pragma unroll
        for (int nt = 0; nt < 8; ++nt) {
            short8 bch = bsm[nt * 64 + lane];
            short8 bsh = bsm[512 + nt * 64 + lane];
            short8 bsl = bsm[1024 + nt * 64 + lane];
            acc[nt] = __builtin_amdgcn_mfma_f32_16x16x32_bf16(za, bch, acc[nt], 0, 0, 0);
            acc[nt] = __builtin_amdgcn_mfma_f32_16x16x32_bf16(xa_h, bsh, acc[nt], 0, 0, 0);
            acc[nt] = __builtin_amdgcn_mfma_f32_16x16x32_bf16(xa_l, bsh, acc[nt], 0, 0, 0);
            acc[nt] = __builtin_amdgcn_mfma_f32_16x16x32_bf16(xa_h, bsl, acc[nt], 0, 0, 0);
        }
    }

    const int orow_base = blockIdx.x * 64 + wave * 16 + quad * 4;
    #pragma unroll
    for (int nt = 0; nt < 8; ++nt) {
        int col = nt * 16 + m;
        float bias = bc[col] + bsk[col];
        #pragma unroll
        for (int r = 0; r < 4; ++r) {
            int orow = orow_base + r;
            if (orow < N) {
                float v = acc[nt][r] + bias;
                v = v > 0.f ? v : 0.1f * (__expf(v) - 1.f);
                out[orow * H + col] = v;
            }
        }
    }
}

// ---------------------------------------------------------------------------
extern "C" void kernel_launch(void* const* d_in, const int* in_sizes, int n_in,
                              void* d_out, int out_size, void* d_ws, size_t ws_size,
                              hipStream_t stream) {
    const float* x   = (const float*)d_in[0];
    const int*   ei  = (const int*)d_in[1];
    const float* Wc  = (const float*)d_in[2];
    const float* bc  = (const float*)d_in[3];
    const float* Wsk = (const float*)d_in[4];
    const float* bsk = (const float*)d_in[5];
    float* out = (float*)d_out;

    const int N = in_sizes[0] / H;       // 100000
    const int E = in_sizes[1] / 2;       // 1600000
    const int nbu = (N + BW - 1) / BW;   // 782 coarse buckets (<=1024)
    const int chunk = (E + NB - 1) / NB; // 6250 edges per partition block
    const int qb = (N + 7) / 8;          // quant blocks

    // workspace layout (byte offsets) -- identical to the proven round-2/3 map
    char* w = (char*)d_ws;
    short8*         wp      = (short8*)w;
    int*            rstart  = (int*)(w + 131072);
    float*          selfw   = (float*)(w + 589824);
    int*            entries = (int*)(w + 1048576);
    unsigned short* wgt     = (unsigned short*)(w + 7471104);
    uint*           xq      = (uint*)(w + 10747904);
    unsigned short* z       = (unsigned short*)(w + 23592960);
    float*          invs    = (float*)(w + 23592960);
    float*          dinv    = (float*)(w + 23992960);
    float*          ainv    = (float*)(w + 24392960);
    int*            cstart  = (int*)(w + 24792960);
    int*            btot    = (int*)(w + 24796160);
    int*            counts  = (int*)(w + 24799360);
    int*            scanned = (int*)(w + 25600128);
    int*            tmp     = (int*)(w + 26400896);

    // quant + W-pack + p1 histogram, fused (histogram blocks appended)
    quant_hist_kernel<<<qb + NB, 256, 0, stream>>>(x, Wc, Wsk, ei, xq, invs, wp,
                                                   counts, N, E, nbu, chunk, qb);

    p2_scan<<<nbu, NB, 0, stream>>>(counts, scanned, btot, nbu);
    p5_scatter<<<NB, 256, 0, stream>>>(ei, btot, scanned, tmp, cstart, E, nbu, chunk);
    csra_kernel<<<nbu, 256, 0, stream>>>(tmp, cstart, invs, rstart, dinv, ainv, selfw, N, E);
    csrb_kernel<<<nbu, 256, 0, stream>>>(tmp, cstart, rstart, dinv, ainv, entries, wgt, N, E);

    // z = sum(w * q[src]) - 128*sumw + selfloop (bf16)
    agg_kernel<<<(N + 3) / 4, 256, 0, stream>>>(entries, wgt, rstart, selfw, xq, z, N);

    // out = ELU(z@Wc + x@Ws + biases)
    gemm_kernel<<<(N + 63) / 64, 256, 0, stream>>>(z, x, wp, bc, bsk, out, N);
}

// Round 5
// 256.400 us; speedup vs baseline: 1.0704x; 1.0704x over previous
//
#include <hip/hip_runtime.h>
#include <hip/hip_bf16.h>
#include <hip/hip_fp16.h>

#define H 128           // H_IN == H_OUT == 128
#define BW 128          // nodes per coarse bucket
#define BSH 7           // log2(BW)
#define NB 256          // partition blocks for counting sort

typedef __attribute__((ext_vector_type(8))) short short8;
typedef __attribute__((ext_vector_type(4))) float f32x4;

__device__ inline unsigned short f2bf(float f) {
    union { float f; unsigned int u; } v; v.f = f;
    unsigned int r = (v.u + 0x7fffu + ((v.u >> 16) & 1u)) >> 16;
    return (unsigned short)r;
}
__device__ inline float bf2f(unsigned short h) {
    union { unsigned int u; float f; } v; v.u = ((unsigned int)h) << 16;
    return v.f;
}

// ---------------------------------------------------------------------------
// Fused: per-row u8 quantization (blocks 0..qb-1), W-pack (blocks 0..7),
// and the p1 edge histogram (blocks qb..qb+NB-1).
__global__ __launch_bounds__(256) void quant_hist_kernel(const float* __restrict__ x,
                                                         const float* __restrict__ Wc,
                                                         const float* __restrict__ Ws,
                                                         const int* __restrict__ ei,
                                                         uint* __restrict__ xq,
                                                         float* __restrict__ invs,
                                                         short8* __restrict__ wp,
                                                         int* __restrict__ counts,
                                                         int N, int E, int nbu,
                                                         int chunk, int qb) {
    __shared__ int h[1024];
    if (blockIdx.x >= qb) {
        // ---- p1 histogram role ----
        const int b = blockIdx.x - qb;
        for (int i = threadIdx.x; i < nbu; i += 256) h[i] = 0;
        __syncthreads();
        const int lo = b * chunk;
        const int hi = min(E, lo + chunk);
        for (int e = lo + threadIdx.x; e < hi; e += 256)
            atomicAdd(&h[ei[E + e] >> BSH], 1);
        __syncthreads();
        for (int i = threadIdx.x; i < nbu; i += 256) counts[b * nbu + i] = h[i];
        return;
    }
    // ---- quant role ----
    int node = blockIdx.x * 8 + (threadIdx.x >> 5);
    if (node < N) {
        int l32 = threadIdx.x & 31;
        float4 v = ((const float4*)x)[node * 32 + l32];
        float m = fmaxf(fmaxf(fabsf(v.x), fabsf(v.y)), fmaxf(fabsf(v.z), fabsf(v.w)));
        #pragma unroll
        for (int mk = 1; mk < 32; mk <<= 1) m = fmaxf(m, __shfl_xor(m, mk));
        m = fmaxf(m, 1e-30f);
        float s = 127.0f / m;
        int q0 = min(255, max(0, (int)rintf(v.x * s) + 128));
        int q1 = min(255, max(0, (int)rintf(v.y * s) + 128));
        int q2 = min(255, max(0, (int)rintf(v.z * s) + 128));
        int q3 = min(255, max(0, (int)rintf(v.w * s) + 128));
        xq[node * 32 + l32] = (uint)q0 | ((uint)q1 << 8) | ((uint)q2 << 16) | ((uint)q3 << 24);
        if (l32 == 0) invs[node] = m / 127.0f;
    }
    if (blockIdx.x < 8) {
        // ---- W-pack role ----
        int t = blockIdx.x * 256 + threadIdx.x;   // 0..2047
        int lane = t & 63;
        int nt = (t >> 6) & 7;
        int ks = t >> 9;
        int kbase = ks * 32 + (lane >> 4) * 8;
        int col = nt * 16 + (lane & 15);
        short8 whc, whs, wls;
        #pragma unroll
        for (int j = 0; j < 8; ++j) {
            float wc = Wc[(kbase + j) * H + col];
            float ws = Ws[(kbase + j) * H + col];
            unsigned short hc = f2bf(wc);
            unsigned short hs = f2bf(ws);
            whc[j] = (short)hc;
            whs[j] = (short)hs;
            wls[j] = (short)f2bf(ws - bf2f(hs));
        }
        int base = (ks * 8 + nt) * 64 + lane;
        wp[base] = whc;
        wp[2048 + base] = whs;
        wp[4096 + base] = wls;
    }
}

// P2: per bucket, exclusive scan of its NB block-counts
__global__ __launch_bounds__(NB) void p2_scan(const int* __restrict__ counts,
                                              int* __restrict__ scanned,
                                              int* __restrict__ btot, int nbu) {
    __shared__ int s[NB];
    const int k = blockIdx.x, t = threadIdx.x;
    int v = counts[t * nbu + k];
    s[t] = v;
    __syncthreads();
    for (int off = 1; off < NB; off <<= 1) {
        int a = (t >= off) ? s[t - off] : 0;
        __syncthreads();
        s[t] += a;
        __syncthreads();
    }
    scanned[t * nbu + k] = s[t] - v;
    if (t == NB - 1) btot[k] = s[t];
}

// P5: scatter packed edges into exact slots (no global atomics).
__global__ __launch_bounds__(256) void p5_scatter(const int* __restrict__ ei,
                                                  const int* __restrict__ btot,
                                                  const int* __restrict__ scanned,
                                                  int* __restrict__ tmp,
                                                  int* __restrict__ cstart,
                                                  int E, int nbu, int chunk) {
    __shared__ int sc[1024];
    __shared__ int part[256];
    __shared__ int lb[1024];
    const int t = threadIdx.x;
    const int b = blockIdx.x;
    const int base = t * 4;
    int v0 = (base + 0 < nbu) ? btot[base + 0] : 0;
    int v1 = (base + 1 < nbu) ? btot[base + 1] : 0;
    int v2 = (base + 2 < nbu) ? btot[base + 2] : 0;
    int v3 = (base + 3 < nbu) ? btot[base + 3] : 0;
    int s1 = v0 + v1, s2 = s1 + v2, s3 = s2 + v3;
    part[t] = s3;
    __syncthreads();
    for (int off = 1; off < 256; off <<= 1) {
        int a = (t >= off) ? part[t - off] : 0;
        __syncthreads();
        part[t] += a;
        __syncthreads();
    }
    int add = (t > 0) ? part[t - 1] : 0;
    sc[base + 0] = add;
    sc[base + 1] = add + v0;
    sc[base + 2] = add + s1;
    sc[base + 3] = add + s2;
    __syncthreads();
    if (b == 0) {
        for (int k = t; k < nbu; k += 256) cstart[k] = sc[k];
        if (t == 0) cstart[nbu] = E;
    }
    for (int k = t; k < nbu; k += 256) lb[k] = sc[k] + scanned[b * nbu + k];
    __syncthreads();
    const int lo = b * chunk;
    const int hi = min(E, lo + chunk);
    for (int e = lo + t; e < hi; e += 256) {
        int s = ei[e], d = ei[E + e];
        int slot = atomicAdd(&lb[d >> BSH], 1);
        tmp[slot] = ((d & (BW - 1)) << 17) | s;
    }
}

// csrA: per bucket, local histogram + parallel scan -> rstart, dinv, ainv, selfw
__global__ __launch_bounds__(256) void csra_kernel(const int* __restrict__ tmp,
                                                   const int* __restrict__ cstart,
                                                   const float* __restrict__ invs,
                                                   int* __restrict__ rstart,
                                                   float* __restrict__ dinv,
                                                   float* __restrict__ ainv,
                                                   float* __restrict__ selfw,
                                                   int N, int E) {
    __shared__ int ldeg[BW];
    __shared__ int lscan[BW];   // inclusive scan
    const int b = blockIdx.x;
    const int nstart = b << BSH;
    const int estart = cstart[b];
    const int eend = cstart[b + 1];
    const int t = threadIdx.x;

    if (t < BW) ldeg[t] = 0;
    __syncthreads();
    for (int i = estart + t; i < eend; i += 256)
        atomicAdd(&ldeg[(tmp[i] >> 17) & (BW - 1)], 1);
    __syncthreads();
    if (t < BW) lscan[t] = ldeg[t];
    __syncthreads();
    #pragma unroll
    for (int off = 1; off < BW; off <<= 1) {
        int a = 0;
        if (t < BW && t >= off) a = lscan[t - off];
        __syncthreads();
        if (t < BW) lscan[t] += a;
        __syncthreads();
    }
    if (t < BW) {
        int excl = lscan[t] - ldeg[t];
        int n = nstart + t;
        if (n < N) {
            float iv = invs[n];
            float dv = rsqrtf((float)ldeg[t] + 2.0f);
            rstart[n] = estart + excl;
            dinv[n] = dv;
            ainv[n] = dv * iv;
            selfw[n] = 2.0f * dv * dv * iv;   // self-loop weight incl dequant scale
        }
    }
    if (b == 0 && t == 0) rstart[N] = E;
}

// csrB: scatter src + precomputed f16 edge weight into final CSR slots.
__global__ __launch_bounds__(256) void csrb_kernel(const int* __restrict__ tmp,
                                                   const int* __restrict__ cstart,
                                                   const int* __restrict__ rstart,
                                                   const float* __restrict__ dinv,
                                                   const float* __restrict__ ainv,
                                                   int* __restrict__ entries,
                                                   unsigned short* __restrict__ wgt,
                                                   int N, int E) {
    __shared__ int lcur[BW];
    __shared__ float ldv[BW];
    const int b = blockIdx.x;
    const int nstart = b << BSH;
    const int t = threadIdx.x;
    if (t < BW) {
        int n = nstart + t;
        lcur[t] = (n < N) ? rstart[n] : 0;
        ldv[t] = (n < N) ? dinv[n] : 0.f;
    }
    __syncthreads();
    const int estart = cstart[b];
    const int eend = cstart[b + 1];
    for (int i = estart + t; i < eend; i += 256) {
        int v = tmp[i];
        int ld = (v >> 17) & (BW - 1);
        int src = v & 0x1FFFF;
        float w = ainv[src] * ldv[ld];
        int slot = atomicAdd(&lcur[ld], 1);
        entries[slot] = src;
        wgt[slot] = __half_as_ushort(__float2half(w));
    }
}

// ---------------------------------------------------------------------------
// Gather aggregation on u8 x. ONE QUARTER-WAVE (16 lanes) PER NODE.
// Each quarter strip-loads 16 of its node's edges coalesced, then broadcasts
// (src,w) via __shfl(.,j,16) and gathers uint2 (8 features/lane). 16 lanes x
// 8 features = all 128 features -> accumulators are complete per lane, NO
// cross-lane reduce, full-wave coalesced store, and 4 independent node
// chains per wave (4x the memory-level parallelism of 1-node-per-wave).
// wv==0 padding slots are lane-predicated off so they issue no gathers.
__global__ __launch_bounds__(256) void agg_kernel(const int* __restrict__ entries,
                                                  const unsigned short* __restrict__ wgt,
                                                  const int* __restrict__ rstart,
                                                  const float* __restrict__ selfw,
                                                  const uint* __restrict__ xq,
                                                  unsigned short* __restrict__ z, int N) {
    int node = blockIdx.x * 16 + (threadIdx.x >> 4);
    if (node >= N) return;
    const int l16 = threadIdx.x & 15;
    const uint2* x2 = (const uint2*)xq;   // 8 features per element, 16 per row

    // independent early loads: overlap with the edge chain
    int start = rstart[node];
    int end = rstart[node + 1];
    float sw = selfw[node];
    uint2 qs = x2[node * 16 + l16];

    float a0 = 0.f, a1 = 0.f, a2 = 0.f, a3 = 0.f;
    float a4 = 0.f, a5 = 0.f, a6 = 0.f, a7 = 0.f;
    float sumw = 0.f;

    for (int c = start; c < end; c += 16) {
        int rem = end - c;
        int src = 0;
        float w = 0.f;
        if (l16 < rem) {
            src = entries[c + l16];
            w = __half2float(__ushort_as_half(wgt[c + l16]));
        }
        #pragma unroll 4
        for (int j = 0; j < 16; ++j) {
            int ss = __shfl(src, j, 16);
            float wv = __shfl(w, j, 16);   // 0 for padding slots
            if (wv != 0.f) {
                uint2 q = x2[ss * 16 + l16];
                sumw += wv;
                a0 += wv * (float)(q.x & 0xffu);
                a1 += wv * (float)((q.x >> 8) & 0xffu);
                a2 += wv * (float)((q.x >> 16) & 0xffu);
                a3 += wv * (float)(q.x >> 24);
                a4 += wv * (float)(q.y & 0xffu);
                a5 += wv * (float)((q.y >> 8) & 0xffu);
                a6 += wv * (float)((q.y >> 16) & 0xffu);
                a7 += wv * (float)(q.y >> 24);
            }
        }
    }

    // self-loop from own quantized row (accumulators already complete)
    sumw += sw;
    a0 += sw * (float)(qs.x & 0xffu);
    a1 += sw * (float)((qs.x >> 8) & 0xffu);
    a2 += sw * (float)((qs.x >> 16) & 0xffu);
    a3 += sw * (float)(qs.x >> 24);
    a4 += sw * (float)(qs.y & 0xffu);
    a5 += sw * (float)((qs.y >> 8) & 0xffu);
    a6 += sw * (float)((qs.y >> 16) & 0xffu);
    a7 += sw * (float)(qs.y >> 24);

    float off = 128.f * sumw;
    uint4 o;
    o.x = (uint)f2bf(a0 - off) | ((uint)f2bf(a1 - off) << 16);
    o.y = (uint)f2bf(a2 - off) | ((uint)f2bf(a3 - off) << 16);
    o.z = (uint)f2bf(a4 - off) | ((uint)f2bf(a5 - off) << 16);
    o.w = (uint)f2bf(a6 - off) | ((uint)f2bf(a7 - off) << 16);
    ((uint4*)z)[node * 16 + l16] = o;
}

// ---------------------------------------------------------------------------
// MFMA GEMM: out = ELU( z@Wc + x@Ws + bc + bsk ), split-bf16 on the x path.
// wp staged per-ks in LDS (kept from round-4: accounting showed ~-7us).
__global__ __launch_bounds__(256) void gemm_kernel(const unsigned short* __restrict__ zb,
                                                   const float* __restrict__ x,
                                                   const short8* __restrict__ wp,
                                                   const float* __restrict__ bc,
                                                   const float* __restrict__ bsk,
                                                   float* __restrict__ out, int N) {
    __shared__ short8 bsm[1536];   // 3 planes x 8 nt x 64 lanes = 24KB
    const int tid = threadIdx.x;
    const int lane = tid & 63;
    const int wave = tid >> 6;
    const int m = lane & 15;
    const int quad = lane >> 4;
    const int row = blockIdx.x * 64 + wave * 16 + m;
    const bool rowok = row < N;

    f32x4 acc[8];
    #pragma unroll
    for (int i = 0; i < 8; ++i) acc[i] = (f32x4){0.f, 0.f, 0.f, 0.f};

    #pragma unroll
    for (int ks = 0; ks < 4; ++ks) {
        const int k0 = ks * 32 + quad * 8;
        short8 za = {0, 0, 0, 0, 0, 0, 0, 0};
        short8 xa_h = {0, 0, 0, 0, 0, 0, 0, 0};
        short8 xa_l = {0, 0, 0, 0, 0, 0, 0, 0};
        if (rowok) {
            za = ((const short8*)zb)[(row * H + k0) >> 3];
            float4 a = *(const float4*)&x[row * H + k0];
            float4 b = *(const float4*)&x[row * H + k0 + 4];
            float xv[8] = {a.x, a.y, a.z, a.w, b.x, b.y, b.z, b.w};
            #pragma unroll
            for (int j = 0; j < 8; ++j) {
                unsigned short h = f2bf(xv[j]);
                xa_h[j] = (short)h;
                xa_l[j] = (short)f2bf(xv[j] - bf2f(h));
            }
        }
        __syncthreads();
        #pragma unroll
        for (int p = 0; p < 3; ++p) {
            bsm[p * 512 + tid]       = wp[p * 2048 + ks * 512 + tid];
            bsm[p * 512 + 256 + tid] = wp[p * 2048 + ks * 512 + 256 + tid];
        }
        __syncthreads();
        #pragma unroll
        for (int nt = 0; nt < 8; ++nt) {
            short8 bch = bsm[nt * 64 + lane];
            short8 bsh = bsm[512 + nt * 64 + lane];
            short8 bsl = bsm[1024 + nt * 64 + lane];
            acc[nt] = __builtin_amdgcn_mfma_f32_16x16x32_bf16(za, bch, acc[nt], 0, 0, 0);
            acc[nt] = __builtin_amdgcn_mfma_f32_16x16x32_bf16(xa_h, bsh, acc[nt], 0, 0, 0);
            acc[nt] = __builtin_amdgcn_mfma_f32_16x16x32_bf16(xa_l, bsh, acc[nt], 0, 0, 0);
            acc[nt] = __builtin_amdgcn_mfma_f32_16x16x32_bf16(xa_h, bsl, acc[nt], 0, 0, 0);
        }
    }

    const int orow_base = blockIdx.x * 64 + wave * 16 + quad * 4;
    #pragma unroll
    for (int nt = 0; nt < 8; ++nt) {
        int col = nt * 16 + m;
        float bias = bc[col] + bsk[col];
        #pragma unroll
        for (int r = 0; r < 4; ++r) {
            int orow = orow_base + r;
            if (orow < N) {
                float v = acc[nt][r] + bias;
                v = v > 0.f ? v : 0.1f * (__expf(v) - 1.f);
                out[orow * H + col] = v;
            }
        }
    }
}

// ---------------------------------------------------------------------------
extern "C" void kernel_launch(void* const* d_in, const int* in_sizes, int n_in,
                              void* d_out, int out_size, void* d_ws, size_t ws_size,
                              hipStream_t stream) {
    const float* x   = (const float*)d_in[0];
    const int*   ei  = (const int*)d_in[1];
    const float* Wc  = (const float*)d_in[2];
    const float* bc  = (const float*)d_in[3];
    const float* Wsk = (const float*)d_in[4];
    const float* bsk = (const float*)d_in[5];
    float* out = (float*)d_out;

    const int N = in_sizes[0] / H;       // 100000
    const int E = in_sizes[1] / 2;       // 1600000
    const int nbu = (N + BW - 1) / BW;   // 782 coarse buckets (<=1024)
    const int chunk = (E + NB - 1) / NB; // 6250 edges per partition block
    const int qb = (N + 7) / 8;          // quant blocks

    // workspace layout (byte offsets) -- identical to the proven round-2/3/4 map
    char* w = (char*)d_ws;
    short8*         wp      = (short8*)w;
    int*            rstart  = (int*)(w + 131072);
    float*          selfw   = (float*)(w + 589824);
    int*            entries = (int*)(w + 1048576);
    unsigned short* wgt     = (unsigned short*)(w + 7471104);
    uint*           xq      = (uint*)(w + 10747904);
    unsigned short* z       = (unsigned short*)(w + 23592960);
    float*          invs    = (float*)(w + 23592960);
    float*          dinv    = (float*)(w + 23992960);
    float*          ainv    = (float*)(w + 24392960);
    int*            cstart  = (int*)(w + 24792960);
    int*            btot    = (int*)(w + 24796160);
    int*            counts  = (int*)(w + 24799360);
    int*            scanned = (int*)(w + 25600128);
    int*            tmp     = (int*)(w + 26400896);

    // quant + W-pack + p1 histogram, fused (histogram blocks appended)
    quant_hist_kernel<<<qb + NB, 256, 0, stream>>>(x, Wc, Wsk, ei, xq, invs, wp,
                                                   counts, N, E, nbu, chunk, qb);

    p2_scan<<<nbu, NB, 0, stream>>>(counts, scanned, btot, nbu);
    p5_scatter<<<NB, 256, 0, stream>>>(ei, btot, scanned, tmp, cstart, E, nbu, chunk);
    csra_kernel<<<nbu, 256, 0, stream>>>(tmp, cstart, invs, rstart, dinv, ainv, selfw, N, E);
    csrb_kernel<<<nbu, 256, 0, stream>>>(tmp, cstart, rstart, dinv, ainv, entries, wgt, N, E);

    // z = sum(w * q[src]) - 128*sumw + selfloop (bf16)
    agg_kernel<<<(N + 15) / 16, 256, 0, stream>>>(entries, wgt, rstart, selfw, xq, z, N);

    // out = ELU(z@Wc + x@Ws + biases)
    gemm_kernel<<<(N + 63) / 64, 256, 0, stream>>>(z, x, wp, bc, bsk, out, N);
}